// Round 3
// baseline (6772.977 us; speedup 1.0000x reference)
//
#include <hip/hip_runtime.h>

#define TT 1024
#define BB 256
#define CC 41

__device__ __forceinline__ float sigf(float x) {
    float t = __builtin_amdgcn_exp2f(-1.4426950408889634f * x);
    return __builtin_amdgcn_rcpf(1.0f + t);
}
__device__ __forceinline__ float tanhf_fast(float x) {
    float t = __builtin_amdgcn_exp2f(2.8853900817779268f * x);
    return fmaf(-2.0f, __builtin_amdgcn_rcpf(t + 1.0f), 1.0f);
}
__device__ __forceinline__ float lane_bcast(float v, int k) {
    return __uint_as_float(__builtin_amdgcn_readlane(__float_as_uint(v), k));
}

// ---------------------------------------------------------------------------
// Register-resident fused LSTM. One (batch row, direction) per block,
// 256 threads = 256 gates, 1 gate/thread. The FULL weight row (wx[K]+wh[64])
// is held in VGPRs for the whole T loop, enforced by an opaque asm pin so the
// compiler cannot rematerialize the loads (round-0: remat -> 67 GB/layer L2
// traffic, 1.95 ms; round-1: launch_bounds(,2) -> scratch spill, 19 GB HBM).
// launch_bounds(256,1) allows up to 512 VGPRs; need ~230.
//
// Step structure (1 barrier/step, proven in round-1):
//  - act[] double-buffered; c/h update replicated across the 4 waves with
//    h in lane-registers (lane u of every wave holds h_u) -> no hcur LDS,
//    no wave0-only tail; h broadcast to FMAs via v_readlane (SGPR operand).
//  - x_t staged through a 3-deep rotating LDS buffer, prefetched 2 steps
//    ahead (issue at top of step s, ds_write just before the barrier);
//    consumed via broadcast ds_read_b128 (off the VALU pipe).
//  - act ds_reads issue first; the x-FMA block hides their latency before
//    the c/h update consumes them.
// ---------------------------------------------------------------------------
template <int K>
__global__ __launch_bounds__(256, 1) void lstm_reg(
    const float* __restrict__ xin,   // [B,T,K]
    const float* __restrict__ w_ih,  // [2,256,K]
    const float* __restrict__ w_hh,  // [2,256,64]
    const float* __restrict__ bias,  // [2,256]
    float* __restrict__ hout)        // [B,T,128], dir writes its 64-half
{
    constexpr int KP = (K + 3) & ~3;   // padded x-row length (16B-aligned rows)
    const int b = blockIdx.x;
    const int dir = blockIdx.y;
    const int tid = threadIdx.x;
    const int u = tid & 63;

    float wx[K];
    float wh[64];
    {
        const float* wr = w_ih + ((size_t)dir * 256 + tid) * K;
        if constexpr ((K & 3) == 0) {
            const float4* wr4 = (const float4*)wr;
#pragma unroll
            for (int q = 0; q < K / 4; ++q) {
                const float4 v = wr4[q];
                wx[4 * q + 0] = v.x; wx[4 * q + 1] = v.y;
                wx[4 * q + 2] = v.z; wx[4 * q + 3] = v.w;
            }
        } else {
#pragma unroll
            for (int k = 0; k < K; ++k) wx[k] = wr[k];
        }
        const float4* hr4 = (const float4*)(w_hh + ((size_t)dir * 256 + tid) * 64);
#pragma unroll
        for (int q = 0; q < 16; ++q) {
            const float4 v = hr4[q];
            wh[4 * q + 0] = v.x; wh[4 * q + 1] = v.y;
            wh[4 * q + 2] = v.z; wh[4 * q + 3] = v.w;
        }
    }
    // Opaque pin: values become asm outputs -> cannot be re-loaded from
    // memory; with the 512-VGPR budget they stay register-resident.
#pragma unroll
    for (int k = 0; k < K; ++k) asm volatile("" : "+v"(wx[k]));
#pragma unroll
    for (int k = 0; k < 64; ++k) asm volatile("" : "+v"(wh[k]));

    const float bg = bias[dir * 256 + tid];

    __shared__ __align__(16) float xs[3][KP];   // rotating x_t staging
    __shared__ float act[2][256];               // double-buffered gate acts

    const float* xb = xin + (size_t)b * TT * K;
    float* hob = hout + (size_t)b * TT * 128 + dir * 64;

    // prologue: stage x for s=0,1; zero pad lanes; zero act[1] so the
    // unconditional step-0 "previous update" is a no-op (c,h stay 0).
    if (tid < K) {
        const int t0 = dir ? (TT - 1) : 0;
        const int t1 = dir ? (TT - 2) : 1;
        xs[0][tid] = xb[(size_t)t0 * K + tid];
        xs[1][tid] = xb[(size_t)t1 * K + tid];
    }
    if (KP > K && tid >= K && tid < KP) {
        xs[0][tid] = 0.f; xs[1][tid] = 0.f; xs[2][tid] = 0.f;
    }
    act[1][tid] = 0.f;

    float hv = 0.f, c = 0.f;
    int rc = 0, rw = 2;   // xs read index (s%3) and write index ((s+2)%3)
    __syncthreads();

    for (int s = 0; s < TT; ++s) {
        // ---- issue prefetch of x_{s+2} (ds_write at loop bottom) ----
        const bool pf = (s + 2 < TT) && (tid < K);
        float xf = 0.f;
        if (pf) {
            const int tp = dir ? (TT - 3 - s) : (s + 2);
            xf = xb[(size_t)tp * K + tid];
        }

        // ---- previous step's activations: issue LDS reads first ----
        const float* ab = act[(s + 1) & 1];
        const float iv = ab[u];
        const float fv = ab[64 + u];
        const float gv = ab[128 + u];
        const float ov = ab[192 + u];

        // ---- x part: broadcast float4 reads from staged LDS row ----
        float ap0 = bg, ap1 = 0.f, ap2 = 0.f, ap3 = 0.f;
        const float4* xv4 = (const float4*)xs[rc];
#pragma unroll
        for (int q = 0; q < KP / 4; ++q) {
            const float4 xv = xv4[q];
            ap0 = fmaf(xv.x, wx[4 * q + 0], ap0);
            if (4 * q + 1 < K) ap1 = fmaf(xv.y, wx[4 * q + 1], ap1);
            if (4 * q + 2 < K) ap2 = fmaf(xv.z, wx[4 * q + 2], ap2);
            if (4 * q + 3 < K) ap3 = fmaf(xv.w, wx[4 * q + 3], ap3);
        }

        // ---- c/h update (replicated across waves; lane u holds unit u) ----
        c = fmaf(fv, c, iv * gv);
        hv = ov * tanhf_fast(c);
        if (s && tid < 64) {
            const int tprev = dir ? (TT - s) : (s - 1);
            hob[(size_t)tprev * 128 + u] = hv;   // fire-and-forget
        }

        // ---- h part: readlane broadcast from register-resident h ----
#pragma unroll
        for (int k = 0; k < 64; ++k) {
            const float hk = lane_bcast(hv, k);
            if ((k & 3) == 0)      ap0 = fmaf(hk, wh[k], ap0);
            else if ((k & 3) == 1) ap1 = fmaf(hk, wh[k], ap1);
            else if ((k & 3) == 2) ap2 = fmaf(hk, wh[k], ap2);
            else                   ap3 = fmaf(hk, wh[k], ap3);
        }

        // ---- activation (gate order i,f,g,o in 64-blocks; wave-uniform) ----
        const float a = (ap0 + ap1) + (ap2 + ap3);
        act[s & 1][tid] = ((tid >> 6) == 2) ? tanhf_fast(a) : sigf(a);

        // ---- land the prefetched x (vmcnt waited here, not at use) ----
        if (pf) xs[rw][tid] = xf;
        __syncthreads();

        rc = (rc == 2) ? 0 : rc + 1;
        rw = (rw == 2) ? 0 : rw + 1;
    }

    // epilogue: final c/h update + store of h at the last time index
    {
        const float* ab = act[(TT - 1) & 1];
        const float cf = fmaf(ab[64 + u], c, ab[u] * ab[128 + u]);
        const float hf = ab[192 + u] * tanhf_fast(cf);
        if (tid < 64) {
            const int tlast = dir ? 0 : (TT - 1);
            hob[(size_t)tlast * 128 + u] = hf;
        }
    }
}

// emissions = feats @ lin_w^T + lin_b ; block tile = 64 (b,t) rows x 41 classes
__global__ __launch_bounds__(256, 2) void emis_kernel(
    const float* __restrict__ feats,  // [B*T,128]
    const float* __restrict__ lw,     // [41,128]
    const float* __restrict__ lb,     // [41]
    float* __restrict__ e)            // [B*T,41]
{
    __shared__ float sf[64 * 132];
    __shared__ float swt[41 * 132];
    const int tid = threadIdx.x;
    const size_t bt0 = (size_t)blockIdx.x * 64;

    const float4* fs = (const float4*)(feats + bt0 * 128);
#pragma unroll
    for (int q = 0; q < 8; ++q) {
        const int idx = tid + q * 256;
        const int row = idx >> 5, col = idx & 31;
        *(float4*)&sf[row * 132 + col * 4] = fs[idx];
    }
    for (int idx = tid; idx < 41 * 32; idx += 256) {
        const int row = idx >> 5, col = idx & 31;
        *(float4*)&swt[row * 132 + col * 4] = ((const float4*)lw)[idx];
    }
    __syncthreads();

    const int btg = tid >> 4;
    const int cg = tid & 15;
    const int c0 = cg * 3;
    float acc[4][3];
#pragma unroll
    for (int i = 0; i < 4; ++i)
#pragma unroll
        for (int j = 0; j < 3; ++j) acc[i][j] = 0.f;

    for (int k = 0; k < 128; k += 4) {
        float4 fv[4], wv[3];
#pragma unroll
        for (int i = 0; i < 4; ++i) fv[i] = *(const float4*)&sf[(btg * 4 + i) * 132 + k];
#pragma unroll
        for (int j = 0; j < 3; ++j) {
            const int c = (c0 + j < CC) ? (c0 + j) : (CC - 1);
            wv[j] = *(const float4*)&swt[c * 132 + k];
        }
#pragma unroll
        for (int i = 0; i < 4; ++i)
#pragma unroll
            for (int j = 0; j < 3; ++j) {
                acc[i][j] = fmaf(fv[i].x, wv[j].x, acc[i][j]);
                acc[i][j] = fmaf(fv[i].y, wv[j].y, acc[i][j]);
                acc[i][j] = fmaf(fv[i].z, wv[j].z, acc[i][j]);
                acc[i][j] = fmaf(fv[i].w, wv[j].w, acc[i][j]);
            }
    }
    __syncthreads();
    float* so = sf;
#pragma unroll
    for (int i = 0; i < 4; ++i)
#pragma unroll
        for (int j = 0; j < 3; ++j) {
            const int c = c0 + j;
            if (c < CC) so[(btg * 4 + i) * CC + c] = acc[i][j] + lb[c];
        }
    __syncthreads();
    float* eo = e + bt0 * CC;
    for (int q = tid; q < 64 * CC; q += 256) eo[q] = so[q];
}

// One wave per batch row; backpointers in LDS; in-kernel backtrace.
__global__ __launch_bounds__(64, 1) void viterbi_kernel(
    const float* __restrict__ e, const float* __restrict__ st,
    const float* __restrict__ en, const float* __restrict__ tr,
    int* __restrict__ out)
{
    const int b = blockIdx.x;
    const int lane = threadIdx.x;
    __shared__ unsigned char bp[TT][CC];
    __shared__ float sc[2][CC];
    const int c = (lane < CC) ? lane : (CC - 1);
    float trc[CC];
#pragma unroll
    for (int p = 0; p < CC; ++p) trc[p] = tr[p * CC + c];

    const float* eb = e + (size_t)b * TT * CC;
    const float NEG = -3.0e38f;
    if (lane < CC) sc[0][lane] = st[lane] + eb[lane];
    __syncthreads();

    for (int t = 1; t < TT; ++t) {
        const float* scp = sc[(t - 1) & 1];
        float best = NEG;
        int bi = 0;
#pragma unroll
        for (int p = 0; p < CC; ++p) {
            const float v = scp[p] + trc[p];
            if (v > best) { best = v; bi = p; }   // strict > : first-index ties
        }
        if (lane < CC) {
            sc[t & 1][lane] = best + eb[(size_t)t * CC + lane];
            bp[t][lane] = (unsigned char)bi;
        }
        __syncthreads();
    }

    float fin = (lane < CC) ? sc[(TT - 1) & 1][lane] + en[lane] : NEG;
    int idx = lane;
#pragma unroll
    for (int off = 32; off; off >>= 1) {
        const float v2 = __shfl_down(fin, off, 64);
        const int i2 = __shfl_down(idx, off, 64);
        if (v2 > fin || (v2 == fin && i2 < idx)) { fin = v2; idx = i2; }
    }
    int tag = __shfl(idx, 0, 64);
    if (lane == 0) {
        int* ob = out + (size_t)b * TT;
        ob[TT - 1] = tag;
        for (int t = TT - 1; t >= 1; --t) {
            tag = bp[t][tag];
            ob[t - 1] = tag;
        }
    }
}

extern "C" void kernel_launch(void* const* d_in, const int* in_sizes, int n_in,
                              void* d_out, int out_size, void* d_ws, size_t ws_size,
                              hipStream_t stream) {
    const float* x       = (const float*)d_in[0];   // [B,T,39]
    const float* w_ih_l0 = (const float*)d_in[1];   // [2,256,39]
    const float* w_hh_l0 = (const float*)d_in[2];   // [2,256,64]
    const float* b_l0    = (const float*)d_in[3];   // [2,256]
    const float* w_ih_r  = (const float*)d_in[4];   // [2,2,256,128]
    const float* w_hh_r  = (const float*)d_in[5];   // [2,2,256,64]
    const float* b_r     = (const float*)d_in[6];   // [2,2,256]
    const float* lin_w   = (const float*)d_in[7];   // [41,128]
    const float* lin_b   = (const float*)d_in[8];   // [41]
    const float* crf_s   = (const float*)d_in[9];   // [41]
    const float* crf_e   = (const float*)d_in[10];  // [41]
    const float* crf_t   = (const float*)d_in[11];  // [41,41]
    int* out = (int*)d_out;

    float* buf0 = (float*)d_ws;                         // [B,T,128] = 128 MiB
    float* buf1 = buf0 + (size_t)BB * TT * 128;         // [B,T,128] = 128 MiB

    dim3 grid(BB, 2);
    // layer 0 (input dim 39): buf0 <- x
    lstm_reg<39><<<grid, 256, 0, stream>>>(x, w_ih_l0, w_hh_l0, b_l0, buf0);
    // layer 1: buf1 <- buf0
    lstm_reg<128><<<grid, 256, 0, stream>>>(buf0, w_ih_r, w_hh_r, b_r, buf1);
    // layer 2: buf0 <- buf1
    lstm_reg<128><<<grid, 256, 0, stream>>>(
        buf1, w_ih_r + 2 * 256 * 128, w_hh_r + 2 * 256 * 64, b_r + 2 * 256, buf0);
    // emissions: buf1 <- buf0, [B*T,41]
    emis_kernel<<<BB * TT / 64, 256, 0, stream>>>(buf0, lin_w, lin_b, buf1);
    // viterbi + backtrace
    viterbi_kernel<<<BB, 64, 0, stream>>>(buf1, crf_s, crf_e, crf_t, out);
}

// Round 5
// 5975.887 us; speedup vs baseline: 1.1334x; 1.1334x over previous
//
#include <hip/hip_runtime.h>

#define TT 1024
#define BB 256
#define CC 41

__device__ __forceinline__ float sigf(float x) {
    float t = __builtin_amdgcn_exp2f(-1.4426950408889634f * x);
    return __builtin_amdgcn_rcpf(1.0f + t);
}
__device__ __forceinline__ float tanhf_fast(float x) {
    float t = __builtin_amdgcn_exp2f(2.8853900817779268f * x);
    return fmaf(-2.0f, __builtin_amdgcn_rcpf(t + 1.0f), 1.0f);
}
__device__ __forceinline__ float lane_bcast(float v, int k) {
    return __uint_as_float(__builtin_amdgcn_readlane(__float_as_uint(v), k));
}

// ---------------------------------------------------------------------------
// Split-K fused LSTM. One (batch row, direction) per block, 512 threads.
// Wave w (of 8): gate block gsel=w>>1 (64 gates, = activation type block),
// K-half = w&1. Per-thread weights: wx[KH] + wh[32] ~ 96 VGPRs (K=128), so
// the whole working set fits ~140 regs -> no spills/remat (round-3 failure:
// 192 weights/thread -> AGPR stash, 3x VALU inflation, 1 wave/SIMD).
// launch_bounds(512,2): 256-reg cap = spill impossible; actual ~140 usage
// still gives 3 waves/SIMD.
//
// Per step (ONE barrier):
//  - each lane reads BOTH halves' partials for its unit u=lane (8 ds_read),
//    does activations + c/h update redundantly per-lane (c,h replicated in
//    every wave's lanes; h_u in lane u).
//  - x-part: same-address broadcast float4 reads from the rotating LDS x
//    buffer (prefetched 2 steps ahead, issue-early/write-late).
//  - h-part: readlane(hv, half*32+j) -- wave-uniform index via readfirstlane
//    (prevents waterfall), 32 FMA.
//  - write this step's partial[s&1][half][gate]; barrier.
// ---------------------------------------------------------------------------
template <int K>
__global__ __launch_bounds__(512, 2) void lstm_half(
    const float* __restrict__ xin,   // [B,T,K]
    const float* __restrict__ w_ih,  // [2,256,K]
    const float* __restrict__ w_hh,  // [2,256,64]
    const float* __restrict__ bias,  // [2,256]
    float* __restrict__ hout)        // [B,T,128], dir writes its 64-half
{
    constexpr int KH = ((K + 7) / 8) * 4;   // per-half K length (mult of 4)
    constexpr int KP = 2 * KH;              // padded x row length
    const int b = blockIdx.x;
    const int dir = blockIdx.y;
    const int tid = threadIdx.x;
    const int lane = tid & 63;
    const int w = tid >> 6;                        // 0..7 (wave-uniform)
    const int halfu = __builtin_amdgcn_readfirstlane(w & 1);   // uniform!
    const int gsel = w >> 1;                       // 0..3 = act block (i,f,g,o)
    const int G = gsel * 64 + lane;                // gate 0..255

    // ---- per-thread half-weights ----
    float wx[KH];
    {
        const float* wr = w_ih + ((size_t)dir * 256 + G) * K + halfu * KH;
#pragma unroll
        for (int j = 0; j < KH; ++j)
            wx[j] = (halfu * KH + j < K) ? wr[j] : 0.f;   // pad tail (K=39)
    }
    float wh[32];
    {
        const float* hr = w_hh + ((size_t)dir * 256 + G) * 64 + halfu * 32;
#pragma unroll
        for (int j = 0; j < 32; ++j) wh[j] = hr[j];
    }
    const float bg = halfu ? 0.f : bias[dir * 256 + G];

    __shared__ __align__(16) float xs[3][KP];     // rotating x_t staging
    __shared__ float part[2][2][256];             // [parity][half][gate]

    const float* xb = xin + (size_t)b * TT * K;
    float* hob = hout + (size_t)b * TT * 128 + dir * 64;

    // prologue: stage x for s=0,1; zero x pad; zero part[1] so step-0's
    // "previous update" is a no-op (sig(0)*tanh(0) terms keep c=h=0).
    if (tid < K) {
        const int t0 = dir ? (TT - 1) : 0;
        const int t1 = dir ? (TT - 2) : 1;
        xs[0][tid] = xb[(size_t)t0 * K + tid];
        xs[1][tid] = xb[(size_t)t1 * K + tid];
    }
    if (KP > K && tid >= K && tid < KP) {
        xs[0][tid] = 0.f; xs[1][tid] = 0.f; xs[2][tid] = 0.f;
    }
    (&part[1][0][0])[tid] = 0.f;   // 512 floats = part[1] entirely

    float c = 0.f, hv = 0.f;
    int rc = 0, rw = 2;
    __syncthreads();

    for (int s = 0; s < TT; ++s) {
        // ---- issue prefetch of x_{s+2} (lands before the barrier) ----
        const bool pf = (s + 2 < TT) && (tid < K);
        float xf = 0.f;
        if (pf) {
            const int tp = dir ? (TT - 3 - s) : (s + 2);
            xf = xb[(size_t)tp * K + tid];
        }

        // ---- previous step's partials -> acts for unit u=lane ----
        const float* pp0 = part[(s + 1) & 1][0];
        const float* pp1 = part[(s + 1) & 1][1];
        const float ai = pp0[lane]       + pp1[lane];
        const float af = pp0[64 + lane]  + pp1[64 + lane];
        const float ag = pp0[128 + lane] + pp1[128 + lane];
        const float ao = pp0[192 + lane] + pp1[192 + lane];
        const float iv = sigf(ai), fv = sigf(af);
        const float gv = tanhf_fast(ag), ov = sigf(ao);
        c = fmaf(fv, c, iv * gv);
        hv = ov * tanhf_fast(c);
        if (s && w == 0) {
            const int tprev = dir ? (TT - s) : (s - 1);
            hob[(size_t)tprev * 128 + lane] = hv;   // fire-and-forget
        }

        // ---- x-part: broadcast float4 reads of this wave's K-half ----
        float ap0 = bg, ap1 = 0.f, ap2 = 0.f, ap3 = 0.f;
        const float4* xv4 = (const float4*)(xs[rc] + halfu * KH);
#pragma unroll
        for (int q = 0; q < KH / 4; ++q) {
            const float4 xv = xv4[q];
            ap0 = fmaf(xv.x, wx[4 * q + 0], ap0);
            ap1 = fmaf(xv.y, wx[4 * q + 1], ap1);
            ap2 = fmaf(xv.z, wx[4 * q + 2], ap2);
            ap3 = fmaf(xv.w, wx[4 * q + 3], ap3);
        }

        // ---- h-part: readlane broadcast, k = halfu*32 + j (uniform) ----
#pragma unroll
        for (int j = 0; j < 32; ++j) {
            const float hk = lane_bcast(hv, halfu * 32 + j);
            if ((j & 3) == 0)      ap0 = fmaf(hk, wh[j], ap0);
            else if ((j & 3) == 1) ap1 = fmaf(hk, wh[j], ap1);
            else if ((j & 3) == 2) ap2 = fmaf(hk, wh[j], ap2);
            else                   ap3 = fmaf(hk, wh[j], ap3);
        }

        // ---- this step's partial ----
        part[s & 1][halfu][G] = (ap0 + ap1) + (ap2 + ap3);

        // ---- land prefetched x ----
        if (pf) xs[rw][tid] = xf;
        __syncthreads();

        rc = (rc == 2) ? 0 : rc + 1;
        rw = (rw == 2) ? 0 : rw + 1;
    }

    // epilogue: h[TT-1] from the last partials
    {
        const float* pp0 = part[(TT - 1) & 1][0];
        const float* pp1 = part[(TT - 1) & 1][1];
        const float ai = pp0[lane]       + pp1[lane];
        const float af = pp0[64 + lane]  + pp1[64 + lane];
        const float ag = pp0[128 + lane] + pp1[128 + lane];
        const float ao = pp0[192 + lane] + pp1[192 + lane];
        const float cf = fmaf(sigf(af), c, sigf(ai) * tanhf_fast(ag));
        const float hf = sigf(ao) * tanhf_fast(cf);
        if (w == 0) {
            const int tlast = dir ? 0 : (TT - 1);
            hob[(size_t)tlast * 128 + lane] = hf;
        }
    }
}

// emissions = feats @ lin_w^T + lin_b ; block tile = 64 (b,t) rows x 41 classes
__global__ __launch_bounds__(256, 2) void emis_kernel(
    const float* __restrict__ feats,  // [B*T,128]
    const float* __restrict__ lw,     // [41,128]
    const float* __restrict__ lb,     // [41]
    float* __restrict__ e)            // [B*T,41]
{
    __shared__ float sf[64 * 132];
    __shared__ float swt[41 * 132];
    const int tid = threadIdx.x;
    const size_t bt0 = (size_t)blockIdx.x * 64;

    const float4* fs = (const float4*)(feats + bt0 * 128);
#pragma unroll
    for (int q = 0; q < 8; ++q) {
        const int idx = tid + q * 256;
        const int row = idx >> 5, col = idx & 31;
        *(float4*)&sf[row * 132 + col * 4] = fs[idx];
    }
    for (int idx = tid; idx < 41 * 32; idx += 256) {
        const int row = idx >> 5, col = idx & 31;
        *(float4*)&swt[row * 132 + col * 4] = ((const float4*)lw)[idx];
    }
    __syncthreads();

    const int btg = tid >> 4;
    const int cg = tid & 15;
    const int c0 = cg * 3;
    float acc[4][3];
#pragma unroll
    for (int i = 0; i < 4; ++i)
#pragma unroll
        for (int j = 0; j < 3; ++j) acc[i][j] = 0.f;

    for (int k = 0; k < 128; k += 4) {
        float4 fv[4], wv[3];
#pragma unroll
        for (int i = 0; i < 4; ++i) fv[i] = *(const float4*)&sf[(btg * 4 + i) * 132 + k];
#pragma unroll
        for (int j = 0; j < 3; ++j) {
            const int c = (c0 + j < CC) ? (c0 + j) : (CC - 1);
            wv[j] = *(const float4*)&swt[c * 132 + k];
        }
#pragma unroll
        for (int i = 0; i < 4; ++i)
#pragma unroll
            for (int j = 0; j < 3; ++j) {
                acc[i][j] = fmaf(fv[i].x, wv[j].x, acc[i][j]);
                acc[i][j] = fmaf(fv[i].y, wv[j].y, acc[i][j]);
                acc[i][j] = fmaf(fv[i].z, wv[j].z, acc[i][j]);
                acc[i][j] = fmaf(fv[i].w, wv[j].w, acc[i][j]);
            }
    }
    __syncthreads();
    float* so = sf;
#pragma unroll
    for (int i = 0; i < 4; ++i)
#pragma unroll
        for (int j = 0; j < 3; ++j) {
            const int c = c0 + j;
            if (c < CC) so[(btg * 4 + i) * CC + c] = acc[i][j] + lb[c];
        }
    __syncthreads();
    float* eo = e + bt0 * CC;
    for (int q = tid; q < 64 * CC; q += 256) eo[q] = so[q];
}

// One wave per batch row; backpointers in LDS; in-kernel backtrace.
__global__ __launch_bounds__(64, 1) void viterbi_kernel(
    const float* __restrict__ e, const float* __restrict__ st,
    const float* __restrict__ en, const float* __restrict__ tr,
    int* __restrict__ out)
{
    const int b = blockIdx.x;
    const int lane = threadIdx.x;
    __shared__ unsigned char bp[TT][CC];
    __shared__ float sc[2][CC];
    const int c = (lane < CC) ? lane : (CC - 1);
    float trc[CC];
#pragma unroll
    for (int p = 0; p < CC; ++p) trc[p] = tr[p * CC + c];

    const float* eb = e + (size_t)b * TT * CC;
    const float NEG = -3.0e38f;
    if (lane < CC) sc[0][lane] = st[lane] + eb[lane];
    __syncthreads();

    for (int t = 1; t < TT; ++t) {
        const float* scp = sc[(t - 1) & 1];
        float best = NEG;
        int bi = 0;
#pragma unroll
        for (int p = 0; p < CC; ++p) {
            const float v = scp[p] + trc[p];
            if (v > best) { best = v; bi = p; }   // strict > : first-index ties
        }
        if (lane < CC) {
            sc[t & 1][lane] = best + eb[(size_t)t * CC + lane];
            bp[t][lane] = (unsigned char)bi;
        }
        __syncthreads();
    }

    float fin = (lane < CC) ? sc[(TT - 1) & 1][lane] + en[lane] : NEG;
    int idx = lane;
#pragma unroll
    for (int off = 32; off; off >>= 1) {
        const float v2 = __shfl_down(fin, off, 64);
        const int i2 = __shfl_down(idx, off, 64);
        if (v2 > fin || (v2 == fin && i2 < idx)) { fin = v2; idx = i2; }
    }
    int tag = __shfl(idx, 0, 64);
    if (lane == 0) {
        int* ob = out + (size_t)b * TT;
        ob[TT - 1] = tag;
        for (int t = TT - 1; t >= 1; --t) {
            tag = bp[t][tag];
            ob[t - 1] = tag;
        }
    }
}

extern "C" void kernel_launch(void* const* d_in, const int* in_sizes, int n_in,
                              void* d_out, int out_size, void* d_ws, size_t ws_size,
                              hipStream_t stream) {
    const float* x       = (const float*)d_in[0];   // [B,T,39]
    const float* w_ih_l0 = (const float*)d_in[1];   // [2,256,39]
    const float* w_hh_l0 = (const float*)d_in[2];   // [2,256,64]
    const float* b_l0    = (const float*)d_in[3];   // [2,256]
    const float* w_ih_r  = (const float*)d_in[4];   // [2,2,256,128]
    const float* w_hh_r  = (const float*)d_in[5];   // [2,2,256,64]
    const float* b_r     = (const float*)d_in[6];   // [2,2,256]
    const float* lin_w   = (const float*)d_in[7];   // [41,128]
    const float* lin_b   = (const float*)d_in[8];   // [41]
    const float* crf_s   = (const float*)d_in[9];   // [41]
    const float* crf_e   = (const float*)d_in[10];  // [41]
    const float* crf_t   = (const float*)d_in[11];  // [41,41]
    int* out = (int*)d_out;

    float* buf0 = (float*)d_ws;                         // [B,T,128] = 128 MiB
    float* buf1 = buf0 + (size_t)BB * TT * 128;         // [B,T,128] = 128 MiB

    dim3 grid(BB, 2);
    // layer 0 (input dim 39): buf0 <- x
    lstm_half<39><<<grid, 512, 0, stream>>>(x, w_ih_l0, w_hh_l0, b_l0, buf0);
    // layer 1: buf1 <- buf0
    lstm_half<128><<<grid, 512, 0, stream>>>(buf0, w_ih_r, w_hh_r, b_r, buf1);
    // layer 2: buf0 <- buf1
    lstm_half<128><<<grid, 512, 0, stream>>>(
        buf1, w_ih_r + 2 * 256 * 128, w_hh_r + 2 * 256 * 64, b_r + 2 * 256, buf0);
    // emissions: buf1 <- buf0, [B*T,41]
    emis_kernel<<<BB * TT / 64, 256, 0, stream>>>(buf0, lin_w, lin_b, buf1);
    // viterbi + backtrace
    viterbi_kernel<<<BB, 64, 0, stream>>>(buf1, crf_s, crf_e, crf_t, out);
}